// Round 3
// baseline (731.938 us; speedup 1.0000x reference)
//
#include <hip/hip_runtime.h>
#include <hip/hip_bf16.h>

#define N_USERS 100000
#define N_ITEMS 50000
#define N_NODES 150000
#define N_REL 5
#define NNZ 2000000
#define D 64
#define B_EVAL 16384
#define MAXSLOTS 32768
#define TOTAL_EDGES (N_REL * NNZ)

// -------- workspace layout (bytes) --------
// map:    int[N_NODES]            @ 0          (600,000 B)
// cnt:    int                     @ 600,064
// agg:    float[MAXSLOTS*320]     @ 600,320    (41,943,040 B)
// logits: float[MAXSLOTS*64]      @ 42,543,360 ( 8,388,608 B)
// total ~ 50.9 MB
#define OFF_MAP 0
#define OFF_CNT 600064
#define OFF_AGG 600320
#define OFF_LOG (600320 + (size_t)MAXSLOTS * 320 * 4)

__global__ __launch_bounds__(256) void build_map(const int* __restrict__ users,
                                                 const int* __restrict__ items,
                                                 int* __restrict__ map,
                                                 int* __restrict__ cnt) {
    int t = blockIdx.x * 256 + threadIdx.x;
    if (t >= 2 * B_EVAL) return;
    int node = (t < B_EVAL) ? users[t] : (N_USERS + items[t - B_EVAL]);
    if (atomicCAS(&map[node], -1, -2) == -1) {
        int idx = atomicAdd(cnt, 1);
        map[node] = idx;   // visible to later kernels at kernel boundary
    }
}

__global__ __launch_bounds__(256) void scatter_edges(const int* __restrict__ rows,
                                                     const int* __restrict__ cols,
                                                     const float* __restrict__ vals,
                                                     const float* __restrict__ uemb,
                                                     const float* __restrict__ iemb,
                                                     const int* __restrict__ map,
                                                     float* __restrict__ agg) {
    long long gid = (long long)blockIdx.x * 256 + threadIdx.x;  // edge id in [0, 5*NNZ)
    int lane = threadIdx.x & 63;

    int pass = 0, ci = -1, c = 0, k = 0;
    float v = 0.0f;
    if (gid < (long long)TOTAL_EDGES) {
        int r = rows[gid];
        ci = map[r];
        if (ci >= 0) {
            pass = 1;
            c = cols[gid];
            v = vals[gid];
            k = (int)(gid / NNZ);
        }
    }
    unsigned long long m = __ballot(pass);
    while (m) {
        int src = __ffsll((unsigned long long)m) - 1;
        m &= m - 1;
        int  cci = __shfl(ci, src);
        int  cc  = __shfl(c, src);
        int  ck  = __shfl(k, src);
        float cv = __shfl(v, src);
        const float* erow = (cc < N_USERS) ? (uemb + (size_t)cc * D)
                                           : (iemb + (size_t)(cc - N_USERS) * D);
        float e = erow[lane];
        unsafeAtomicAdd(&agg[(size_t)cci * (N_REL * D) + ck * D + lane], cv * e);
    }
}

__global__ __launch_bounds__(256) void dense_transform(const float* __restrict__ agg,
                                                       const float* __restrict__ Wrel,
                                                       const float* __restrict__ brel,
                                                       const float* __restrict__ affW,
                                                       const float* __restrict__ affb,
                                                       float* __restrict__ logits) {
    int wave = (blockIdx.x * 256 + threadIdx.x) >> 6;  // one wave per compact slot
    int lane = threadIdx.x & 63;
    int w4   = threadIdx.x >> 6;
    __shared__ float tmp[4][N_REL * D];
    if (wave >= MAXSLOTS) return;

    const float* a = agg + (size_t)wave * (N_REL * D);
    #pragma unroll
    for (int k = 0; k < N_REL; k++) {
        float areg = a[k * D + lane];
        float acc = brel[k * D + lane];
        #pragma unroll
        for (int d = 0; d < D; d++) {
            float ad = __shfl(areg, d);
            acc += ad * Wrel[(k * D + d) * D + lane];
        }
        acc = (acc > 0.0f) ? acc : 0.2f * acc;  // leaky_relu 0.2
        tmp[w4][k * D + lane] = acc;
    }
    __syncthreads();

    float acc = affb[lane];
    #pragma unroll 8
    for (int j = 0; j < N_REL * D; j++) {
        acc += tmp[w4][j] * affW[j * D + lane];
    }
    logits[(size_t)wave * D + lane] = acc;
}

__global__ __launch_bounds__(256) void finalize(const int* __restrict__ users,
                                                const int* __restrict__ items,
                                                const int* __restrict__ map,
                                                const float* __restrict__ logits,
                                                float* __restrict__ out) {
    int wave = (blockIdx.x * 256 + threadIdx.x) >> 6;
    int lane = threadIdx.x & 63;
    if (wave >= B_EVAL) return;
    int cu = map[users[wave]];
    int ci = map[N_USERS + items[wave]];
    float p = logits[(size_t)cu * D + lane] * logits[(size_t)ci * D + lane];
    #pragma unroll
    for (int off = 32; off > 0; off >>= 1) p += __shfl_down(p, off);
    if (lane == 0) out[wave] = p;
}

extern "C" void kernel_launch(void* const* d_in, const int* in_sizes, int n_in,
                              void* d_out, int out_size, void* d_ws, size_t ws_size,
                              hipStream_t stream) {
    const int*   users = (const int*)d_in[0];
    const int*   items = (const int*)d_in[1];
    const int*   rows  = (const int*)d_in[2];
    const int*   cols  = (const int*)d_in[3];
    const float* vals  = (const float*)d_in[4];
    const float* uemb  = (const float*)d_in[5];
    const float* iemb  = (const float*)d_in[6];
    const float* Wrel  = (const float*)d_in[7];
    const float* brel  = (const float*)d_in[8];
    const float* affW  = (const float*)d_in[9];
    const float* affb  = (const float*)d_in[10];
    float* out = (float*)d_out;

    char* ws = (char*)d_ws;
    int*   map    = (int*)(ws + OFF_MAP);
    int*   cnt    = (int*)(ws + OFF_CNT);
    float* agg    = (float*)(ws + OFF_AGG);
    float* logits = (float*)(ws + OFF_LOG);

    // workspace is re-poisoned before every call: re-init every time
    hipMemsetAsync(map, 0xFF, (size_t)N_NODES * sizeof(int), stream);   // map = -1
    hipMemsetAsync(cnt, 0, sizeof(int), stream);
    hipMemsetAsync(agg, 0, (size_t)MAXSLOTS * (N_REL * D) * sizeof(float), stream);

    build_map<<<(2 * B_EVAL + 255) / 256, 256, 0, stream>>>(users, items, map, cnt);
    scatter_edges<<<(TOTAL_EDGES + 255) / 256, 256, 0, stream>>>(rows, cols, vals, uemb, iemb, map, agg);
    dense_transform<<<(MAXSLOTS * 64) / 256, 256, 0, stream>>>(agg, Wrel, brel, affW, affb, logits);
    finalize<<<(B_EVAL * 64) / 256, 256, 0, stream>>>(users, items, map, logits, out);
}